// Round 1
// baseline (45948.306 us; speedup 1.0000x reference)
//
#include <hip/hip_runtime.h>
#include <cstdint>

// ---- problem dims (fixed by reference) ----
#define Hdim 512
#define Bdim 128
#define Tdim 512
#define FUT  32
#define TT   (Tdim + FUT)   // 544
#define NBLK 256
#define NTHR 256

// ---- ws layout (float offsets) ----
#define WP1_OFF   0                                  // [512][512] float4 (gate-packed W_hh1)
#define WP2I_OFF  (WP1_OFF  + Hdim*Hdim*4)           // W_ih2 packed
#define WP2H_OFF  (WP2I_OFF + Hdim*Hdim*4)           // W_hh2 packed
#define B1P_OFF   (WP2H_OFF + Hdim*Hdim*4)           // [512] float4 bias1 (b_ih1+b_hh1)
#define B2P_OFF   (B1P_OFF  + Hdim*4)
#define WX1_OFF   (B2P_OFF  + Hdim*4)                // [512] float4 W_ih1 per gate
#define XT_OFF    (WX1_OFF  + Hdim*4)                // xT[t][b]  (512*128)
#define H1_OFF    (XT_OFF   + Tdim*Bdim)             // 2 ping-pong [512][128]
#define H2_OFF    (H1_OFF   + 2*Hdim*Bdim)
#define OUTB_OFF  (H2_OFF   + 2*Hdim*Bdim)           // [128] current out
#define ARR_OFF   (OUTB_OFF + Bdim)                  // [256] arrive flags (uint)
#define REL_OFF   (ARR_OFF  + NBLK)                  // release word
#define WS_FLOATS (REL_OFF  + 16)

__device__ __forceinline__ float sigm(float v) { return 1.0f / (1.0f + __expf(-v)); }
__device__ __forceinline__ float tanh_fast(float v) {
    v = fminf(fmaxf(v, -20.0f), 20.0f);      // tanh(|20|) == 1.0 in fp32; avoids exp overflow
    float e = __expf(2.0f * v);
    return (e - 1.0f) / (e + 1.0f);
}

// ---------- grid barrier: flag-array arrive, block0 aggregates, release word ----------
__device__ __forceinline__ void grid_barrier(unsigned* arr, unsigned* rel, unsigned phase) {
    __syncthreads();                          // all waves' stores drained to L2 (waitcnt before s_barrier)
    if (threadIdx.x == 0) {
        __threadfence();                      // device-scope release of this block's writes (wbl2)
        __hip_atomic_store(&arr[blockIdx.x], phase, __ATOMIC_RELEASE, __HIP_MEMORY_SCOPE_AGENT);
    }
    if (blockIdx.x == 0) {
        // 256 threads each watch one block's flag (monotonic phases -> no reset)
        while (__hip_atomic_load(&arr[threadIdx.x], __ATOMIC_RELAXED, __HIP_MEMORY_SCOPE_AGENT) < phase)
            __builtin_amdgcn_s_sleep(1);
        __threadfence();                      // acquire: invalidate stale L1/L2 lines
        __syncthreads();
        if (threadIdx.x == 0)
            __hip_atomic_store(rel, phase, __ATOMIC_RELEASE, __HIP_MEMORY_SCOPE_AGENT);
        __syncthreads();
    } else {
        if (threadIdx.x == 0) {
            while (__hip_atomic_load(rel, __ATOMIC_RELAXED, __HIP_MEMORY_SCOPE_AGENT) < phase)
                __builtin_amdgcn_s_sleep(1);
            __threadfence();                  // acquire
        }
        __syncthreads();
    }
}

// ---------- staged mat-vec accumulate: gates += Wp[k] * h[k][bcol], K=512 ----------
// hsrc: [512][128] transposed h.  wp: per-unit gate-packed weights (wave-uniform).
__device__ __forceinline__ void accum_block(const float* hsrc, const float4* wp,
                                            int half, int lane, int tid,
                                            float& ai, float& af, float& ag, float& ao,
                                            float* hlds) {
    for (int kc = 0; kc < Hdim; kc += 128) {
        __syncthreads();   // protect hlds from previous chunk's readers
        {
            // stage 128 rows x 64 cols (this block's batch half) = 32KB, float4 coalesced
            const float4* src = (const float4*)(hsrc + (size_t)kc * Bdim + half * 64);
            #pragma unroll
            for (int pass = 0; pass < 8; ++pass) {
                int idx = pass * 256 + tid;          // float4 index 0..2047
                int r = idx >> 4, c4 = idx & 15;
                ((float4*)hlds)[idx] = src[(size_t)r * 32 + c4];
            }
        }
        __syncthreads();
        #pragma unroll 8
        for (int kk = 0; kk < 128; ++kk) {
            float  hv = hlds[kk * 64 + lane];        // 64 lanes / 32 banks: 2-way = free
            float4 wk = wp[kc + kk];                 // wave-uniform -> s_load_dwordx4
            ai = fmaf(wk.x, hv, ai); af = fmaf(wk.y, hv, af);
            ag = fmaf(wk.z, hv, ag); ao = fmaf(wk.w, hv, ao);
        }
    }
}

// ---------- prep: pack weights gate-major, transpose x, zero state/flags ----------
__global__ void lstm_prep(const float* __restrict__ x,
                          const float* __restrict__ W_ih1, const float* __restrict__ W_hh1,
                          const float* __restrict__ b_ih1, const float* __restrict__ b_hh1,
                          const float* __restrict__ W_ih2, const float* __restrict__ W_hh2,
                          const float* __restrict__ b_ih2, const float* __restrict__ b_hh2,
                          float* __restrict__ ws) {
    int i = blockIdx.x * blockDim.x + threadIdx.x;   // 0..262143
    if (i < Hdim * Hdim) {
        int u = i >> 9, k = i & (Hdim - 1);
        float4 w1, w2i, w2h;
        w1.x  = W_hh1[(0 * Hdim + u) * Hdim + k];  w1.y  = W_hh1[(1 * Hdim + u) * Hdim + k];
        w1.z  = W_hh1[(2 * Hdim + u) * Hdim + k];  w1.w  = W_hh1[(3 * Hdim + u) * Hdim + k];
        w2i.x = W_ih2[(0 * Hdim + u) * Hdim + k];  w2i.y = W_ih2[(1 * Hdim + u) * Hdim + k];
        w2i.z = W_ih2[(2 * Hdim + u) * Hdim + k];  w2i.w = W_ih2[(3 * Hdim + u) * Hdim + k];
        w2h.x = W_hh2[(0 * Hdim + u) * Hdim + k];  w2h.y = W_hh2[(1 * Hdim + u) * Hdim + k];
        w2h.z = W_hh2[(2 * Hdim + u) * Hdim + k];  w2h.w = W_hh2[(3 * Hdim + u) * Hdim + k];
        ((float4*)(ws + WP1_OFF))[i]  = w1;
        ((float4*)(ws + WP2I_OFF))[i] = w2i;
        ((float4*)(ws + WP2H_OFF))[i] = w2h;
    }
    if (i < Hdim) {
        float4 bb1 = { b_ih1[i] + b_hh1[i],           b_ih1[Hdim + i] + b_hh1[Hdim + i],
                       b_ih1[2*Hdim+i] + b_hh1[2*Hdim+i], b_ih1[3*Hdim+i] + b_hh1[3*Hdim+i] };
        float4 bb2 = { b_ih2[i] + b_hh2[i],           b_ih2[Hdim + i] + b_hh2[Hdim + i],
                       b_ih2[2*Hdim+i] + b_hh2[2*Hdim+i], b_ih2[3*Hdim+i] + b_hh2[3*Hdim+i] };
        float4 wx  = { W_ih1[i], W_ih1[Hdim + i], W_ih1[2*Hdim + i], W_ih1[3*Hdim + i] };
        ((float4*)(ws + B1P_OFF))[i] = bb1;
        ((float4*)(ws + B2P_OFF))[i] = bb2;
        ((float4*)(ws + WX1_OFF))[i] = wx;
    }
    if (i < Tdim * Bdim) {                      // 65536: xT + zero h ping buffers (p=0)
        int t = i >> 7, b = i & 127;
        ws[XT_OFF + i] = x[b * Tdim + t];
        ws[H1_OFF + i] = 0.0f;
        ws[H2_OFF + i] = 0.0f;
    }
    if (i < NBLK + 16)                          // arrive flags + release word
        ((unsigned*)(ws + ARR_OFF))[i] = 0u;
}

// ---------- persistent main kernel ----------
__global__ __launch_bounds__(NTHR) void lstm_main(float* ws,
                                                  const float* __restrict__ Wout,
                                                  const float* __restrict__ bout,
                                                  float* __restrict__ out) {
    const int tid  = threadIdx.x;
    const int bid  = blockIdx.x;
    const int w    = tid >> 6;                  // wave 0..3 = local unit
    const int lane = tid & 63;
    const int ug   = bid >> 1;                  // unit group 0..127
    const int half = bid & 1;                   // batch half
    const int u    = __builtin_amdgcn_readfirstlane(ug * 4 + w);  // global unit 0..511
    const int bcol = half * 64 + lane;          // batch index 0..127

    __shared__ float hlds[128 * 64];            // 32KB staging
    __shared__ float partial[4][64];

    unsigned* arr = (unsigned*)(ws + ARR_OFF);
    unsigned* rel = (unsigned*)(ws + REL_OFF);

    const float4* wp1  = (const float4*)(ws + WP1_OFF)  + (size_t)u * Hdim;
    const float4* wp2i = (const float4*)(ws + WP2I_OFF) + (size_t)u * Hdim;
    const float4* wp2h = (const float4*)(ws + WP2H_OFF) + (size_t)u * Hdim;
    const float4 bias1 = ((const float4*)(ws + B1P_OFF))[u];
    const float4 bias2 = ((const float4*)(ws + B2P_OFF))[u];
    const float4 wx1   = ((const float4*)(ws + WX1_OFF))[u];

    float c1 = 0.0f, c2 = 0.0f, xv_fut = 0.0f;
    unsigned phase = 0;

    for (int t = 0; t < TT; ++t) {
        const int p = t & 1;
        const float* h1prev = ws + H1_OFF + p       * (Hdim * Bdim);
        float*       h1next = ws + H1_OFF + (p ^ 1) * (Hdim * Bdim);
        const float* h2prev = ws + H2_OFF + p       * (Hdim * Bdim);
        float*       h2next = ws + H2_OFF + (p ^ 1) * (Hdim * Bdim);

        float xv = (t < Tdim) ? ws[XT_OFF + t * Bdim + bcol] : xv_fut;

        // ---- cell 1: gates = bias + W_ih1*x + W_hh1*h1prev
        float ai = fmaf(wx1.x, xv, bias1.x);
        float af = fmaf(wx1.y, xv, bias1.y);
        float ag = fmaf(wx1.z, xv, bias1.z);
        float ao = fmaf(wx1.w, xv, bias1.w);
        accum_block(h1prev, wp1, half, lane, tid, ai, af, ag, ao, hlds);

        float i1 = sigm(ai), f1 = sigm(af), g1 = tanh_fast(ag), o1 = sigm(ao);
        c1 = fmaf(f1, c1, i1 * g1);
        float h1v = o1 * tanh_fast(c1);
        h1next[(size_t)u * Bdim + bcol] = h1v;

        grid_barrier(arr, rel, ++phase);        // h1(t) visible everywhere

        // ---- cell 2: gates = bias + W_ih2*h1(t) + W_hh2*h2prev
        ai = bias2.x; af = bias2.y; ag = bias2.z; ao = bias2.w;
        accum_block(h1next, wp2i, half, lane, tid, ai, af, ag, ao, hlds);
        accum_block(h2prev, wp2h, half, lane, tid, ai, af, ag, ao, hlds);

        float i2 = sigm(ai), f2 = sigm(af), g2 = tanh_fast(ag), o2 = sigm(ao);
        c2 = fmaf(f2, c2, i2 * g2);
        float h2v = o2 * tanh_fast(c2);
        h2next[(size_t)u * Bdim + bcol] = h2v;

        grid_barrier(arr, rel, ++phase);        // h2(t) visible everywhere

        // ---- out = h2 @ W_out.T + b_out : blocks 0/1 only (others run ahead to next barrier)
        if (bid < 2) {
            float acc = 0.0f;
            const float* hb = h2next + bcol;
            const int k0 = w * 128;             // 4 waves split K
            #pragma unroll 8
            for (int kk = 0; kk < 128; ++kk)
                acc = fmaf(hb[(size_t)(k0 + kk) * Bdim], Wout[k0 + kk], acc);
            partial[w][lane] = acc;
            __syncthreads();
            if (w == 0) {
                float o = partial[0][lane] + partial[1][lane] + partial[2][lane]
                        + partial[3][lane] + bout[0];
                out[(size_t)bcol * TT + t] = o;
                ws[OUTB_OFF + bcol] = o;
            }
            __syncthreads();
        }

        // future phase needs out(t) as next input -> extra barrier starting at t = T-1
        if (t >= Tdim - 1) {
            grid_barrier(arr, rel, ++phase);
            xv_fut = ws[OUTB_OFF + bcol];
        }
    }
}

extern "C" void kernel_launch(void* const* d_in, const int* in_sizes, int n_in,
                              void* d_out, int out_size, void* d_ws, size_t ws_size,
                              hipStream_t stream) {
    const float* x     = (const float*)d_in[0];
    const float* W_ih1 = (const float*)d_in[1];
    const float* W_hh1 = (const float*)d_in[2];
    const float* b_ih1 = (const float*)d_in[3];
    const float* b_hh1 = (const float*)d_in[4];
    const float* W_ih2 = (const float*)d_in[5];
    const float* W_hh2 = (const float*)d_in[6];
    const float* b_ih2 = (const float*)d_in[7];
    const float* b_hh2 = (const float*)d_in[8];
    const float* W_out = (const float*)d_in[9];
    const float* b_out = (const float*)d_in[10];
    float* ws  = (float*)d_ws;
    float* out = (float*)d_out;

    hipLaunchKernelGGL(lstm_prep, dim3(1024), dim3(256), 0, stream,
                       x, W_ih1, W_hh1, b_ih1, b_hh1, W_ih2, W_hh2, b_ih2, b_hh2, ws);
    hipLaunchKernelGGL(lstm_main, dim3(NBLK), dim3(NTHR), 0, stream,
                       ws, W_out, b_out, out);
}

// Round 2
// 45076.962 us; speedup vs baseline: 1.0193x; 1.0193x over previous
//
#include <hip/hip_runtime.h>
#include <cstdint>

// ---- problem dims (fixed by reference) ----
#define Hdim 512
#define Bdim 128
#define Tdim 512
#define FUT  32
#define TT   (Tdim + FUT)   // 544
#define NBLK 256
#define NTHR 256

// ---- ws layout (float offsets) ----
#define WP1_OFF   0                                  // [512][512] float4 (gate-packed W_hh1)
#define WP2I_OFF  (WP1_OFF  + Hdim*Hdim*4)           // W_ih2 packed
#define WP2H_OFF  (WP2I_OFF + Hdim*Hdim*4)           // W_hh2 packed
#define B1P_OFF   (WP2H_OFF + Hdim*Hdim*4)           // [512] float4 bias1 (b_ih1+b_hh1)
#define B2P_OFF   (B1P_OFF  + Hdim*4)
#define WX1_OFF   (B2P_OFF  + Hdim*4)                // [512] float4 W_ih1 per gate
#define XT_OFF    (WX1_OFF  + Hdim*4)                // xT[t][b]  (512*128)
#define H1_OFF    (XT_OFF   + Tdim*Bdim)             // 2 ping-pong [512][128]
#define H2_OFF    (H1_OFF   + 2*Hdim*Bdim)
#define OUTB_OFF  (H2_OFF   + 2*Hdim*Bdim)           // (unused this round)
#define ARR_OFF   (OUTB_OFF + Bdim)                  // [256] arrive flags (uint)
#define REL_OFF   (ARR_OFF  + NBLK)                  // release word
#define WS_FLOATS (REL_OFF  + 16)

__device__ __forceinline__ float sigm(float v) { return 1.0f / (1.0f + __expf(-v)); }
__device__ __forceinline__ float tanh_fast(float v) {
    v = fminf(fmaxf(v, -20.0f), 20.0f);
    float e = __expf(2.0f * v);
    return (e - 1.0f) / (e + 1.0f);
}

// ---------- grid barrier (proven in round 1) ----------
__device__ __forceinline__ void grid_barrier(unsigned* arr, unsigned* rel, unsigned phase) {
    __syncthreads();
    if (threadIdx.x == 0) {
        __threadfence();
        __hip_atomic_store(&arr[blockIdx.x], phase, __ATOMIC_RELEASE, __HIP_MEMORY_SCOPE_AGENT);
    }
    if (blockIdx.x == 0) {
        while (__hip_atomic_load(&arr[threadIdx.x], __ATOMIC_RELAXED, __HIP_MEMORY_SCOPE_AGENT) < phase)
            __builtin_amdgcn_s_sleep(1);
        __threadfence();
        __syncthreads();
        if (threadIdx.x == 0)
            __hip_atomic_store(rel, phase, __ATOMIC_RELEASE, __HIP_MEMORY_SCOPE_AGENT);
        __syncthreads();
    } else {
        if (threadIdx.x == 0) {
            while (__hip_atomic_load(rel, __ATOMIC_RELAXED, __HIP_MEMORY_SCOPE_AGENT) < phase)
                __builtin_amdgcn_s_sleep(1);
            __threadfence();
        }
        __syncthreads();
    }
}

// ---------- matvec: gates += W(lds) * h(global, staged through LDS pipelined) ----------
// hsrc: [512][128] transposed h.  wl: this wave's gate-packed weights in LDS (float4[512]).
__device__ __forceinline__ void matvec4(const float* __restrict__ hsrc, const float4* wl,
                                        int half, int lane, int tid,
                                        float& ai, float& af, float& ag, float& ao,
                                        float* hlds) {
    const float4* src = (const float4*)hsrc + half * 16;   // row stride = 32 float4
    float4 pre[8];
    #pragma unroll
    for (int p = 0; p < 8; ++p) {
        int idx = p * 256 + tid, r = idx >> 4, c = idx & 15;
        pre[p] = src[(size_t)r * 32 + c];
    }
    for (int kc = 0; kc < Hdim; kc += 128) {
        __syncthreads();                               // prev readers of hlds done
        #pragma unroll
        for (int p = 0; p < 8; ++p)
            ((float4*)hlds)[p * 256 + tid] = pre[p];
        __syncthreads();                               // staging visible
        if (kc + 128 < Hdim) {                         // prefetch next chunk DURING compute
            #pragma unroll
            for (int p = 0; p < 8; ++p) {
                int idx = p * 256 + tid, r = idx >> 4, c = idx & 15;
                pre[p] = src[(size_t)(kc + 128 + r) * 32 + c];
            }
        }
        #pragma unroll 8
        for (int kk = 0; kk < 128; ++kk) {
            float  hv = hlds[kk * 64 + lane];          // 2 lanes/bank: free
            float4 wk = wl[kc + kk];                   // wave-uniform LDS broadcast
            ai = fmaf(wk.x, hv, ai); af = fmaf(wk.y, hv, af);
            ag = fmaf(wk.z, hv, ag); ao = fmaf(wk.w, hv, ao);
        }
    }
}

// ---------- out-dot for future phase: every block computes its own feedback ----------
__device__ __forceinline__ float outdot(const float* __restrict__ h2, int half, int lane, int tid,
                                        float* hlds, const float* wout_lds) {
    float acc = 0.0f;
    const float4* src = (const float4*)h2 + half * 16;
    for (int kc = 0; kc < Hdim; kc += 128) {
        __syncthreads();
        #pragma unroll
        for (int p = 0; p < 8; ++p) {
            int idx = p * 256 + tid, r = idx >> 4, c = idx & 15;
            ((float4*)hlds)[idx] = src[(size_t)(kc + r) * 32 + c];
        }
        __syncthreads();
        #pragma unroll 8
        for (int kk = 0; kk < 128; ++kk)
            acc = fmaf(hlds[kk * 64 + lane], wout_lds[kc + kk], acc);
    }
    return acc;
}

// ---------- prep: pack weights gate-major, transpose x, zero state/flags ----------
__global__ void lstm_prep(const float* __restrict__ x,
                          const float* __restrict__ W_ih1, const float* __restrict__ W_hh1,
                          const float* __restrict__ b_ih1, const float* __restrict__ b_hh1,
                          const float* __restrict__ W_ih2, const float* __restrict__ W_hh2,
                          const float* __restrict__ b_ih2, const float* __restrict__ b_hh2,
                          float* __restrict__ ws) {
    int i = blockIdx.x * blockDim.x + threadIdx.x;
    if (i < Hdim * Hdim) {
        int u = i >> 9, k = i & (Hdim - 1);
        float4 w1, w2i, w2h;
        w1.x  = W_hh1[(0 * Hdim + u) * Hdim + k];  w1.y  = W_hh1[(1 * Hdim + u) * Hdim + k];
        w1.z  = W_hh1[(2 * Hdim + u) * Hdim + k];  w1.w  = W_hh1[(3 * Hdim + u) * Hdim + k];
        w2i.x = W_ih2[(0 * Hdim + u) * Hdim + k];  w2i.y = W_ih2[(1 * Hdim + u) * Hdim + k];
        w2i.z = W_ih2[(2 * Hdim + u) * Hdim + k];  w2i.w = W_ih2[(3 * Hdim + u) * Hdim + k];
        w2h.x = W_hh2[(0 * Hdim + u) * Hdim + k];  w2h.y = W_hh2[(1 * Hdim + u) * Hdim + k];
        w2h.z = W_hh2[(2 * Hdim + u) * Hdim + k];  w2h.w = W_hh2[(3 * Hdim + u) * Hdim + k];
        ((float4*)(ws + WP1_OFF))[i]  = w1;
        ((float4*)(ws + WP2I_OFF))[i] = w2i;
        ((float4*)(ws + WP2H_OFF))[i] = w2h;
    }
    if (i < Hdim) {
        float4 bb1 = { b_ih1[i] + b_hh1[i],               b_ih1[Hdim+i] + b_hh1[Hdim+i],
                       b_ih1[2*Hdim+i] + b_hh1[2*Hdim+i], b_ih1[3*Hdim+i] + b_hh1[3*Hdim+i] };
        float4 bb2 = { b_ih2[i] + b_hh2[i],               b_ih2[Hdim+i] + b_hh2[Hdim+i],
                       b_ih2[2*Hdim+i] + b_hh2[2*Hdim+i], b_ih2[3*Hdim+i] + b_hh2[3*Hdim+i] };
        float4 wx  = { W_ih1[i], W_ih1[Hdim+i], W_ih1[2*Hdim+i], W_ih1[3*Hdim+i] };
        ((float4*)(ws + B1P_OFF))[i] = bb1;
        ((float4*)(ws + B2P_OFF))[i] = bb2;
        ((float4*)(ws + WX1_OFF))[i] = wx;
    }
    if (i < Tdim * Bdim) {
        int t = i >> 7, b = i & 127;
        ws[XT_OFF + i] = x[b * Tdim + t];
        ws[H1_OFF + i] = 0.0f;
        ws[H2_OFF + i] = 0.0f;
    }
    if (i < NBLK + 16)
        ((unsigned*)(ws + ARR_OFF))[i] = 0u;
}

// ---------- persistent main kernel ----------
__global__ __launch_bounds__(NTHR) void lstm_main(float* ws,
                                                  const float* __restrict__ Wout,
                                                  const float* __restrict__ bout,
                                                  float* __restrict__ out) {
    const int tid  = threadIdx.x;
    const int bid  = blockIdx.x;
    const int w    = tid >> 6;                  // wave 0..3 = local unit
    const int lane = tid & 63;
    const int ug   = bid >> 1;                  // unit group 0..127
    const int half = bid & 1;                   // batch half
    const int u    = __builtin_amdgcn_readfirstlane(ug * 4 + w);
    const int bcol = half * 64 + lane;

    // LDS: weights resident (immune to L2 inv from barrier fences)
    __shared__ float4 wlds4[4 * 3 * Hdim];      // 96 KB: [wave][mat][k] gate-packed
    __shared__ float  hlds[128 * 64];           // 32 KB h staging
    __shared__ float  wout_lds[Hdim];           // 2 KB
    __shared__ float  partial[4][64];           // 1 KB

    unsigned* arr = (unsigned*)(ws + ARR_OFF);
    unsigned* rel = (unsigned*)(ws + REL_OFF);

    // ---- one-time: pull this block's weights into LDS (coalesced) ----
    {
        const float4* wsrc0 = (const float4*)(ws + WP1_OFF);
        const float4* wsrc1 = (const float4*)(ws + WP2I_OFF);
        const float4* wsrc2 = (const float4*)(ws + WP2H_OFF);
        for (int w2 = 0; w2 < 4; ++w2) {
            const size_t ubase = (size_t)(ug * 4 + w2) * Hdim;
            #pragma unroll
            for (int p = 0; p < 2; ++p) {
                int k = p * 256 + tid;
                wlds4[(w2 * 3 + 0) * Hdim + k] = wsrc0[ubase + k];
                wlds4[(w2 * 3 + 1) * Hdim + k] = wsrc1[ubase + k];
                wlds4[(w2 * 3 + 2) * Hdim + k] = wsrc2[ubase + k];
            }
        }
        wout_lds[tid]       = Wout[tid];
        wout_lds[256 + tid] = Wout[256 + tid];
    }

    const float4* wl1  = wlds4 + (w * 3 + 0) * Hdim;
    const float4* wl2i = wlds4 + (w * 3 + 1) * Hdim;
    const float4* wl2h = wlds4 + (w * 3 + 2) * Hdim;
    const float4 bias1 = ((const float4*)(ws + B1P_OFF))[u];
    const float4 bias2 = ((const float4*)(ws + B2P_OFF))[u];
    const float4 wx1   = ((const float4*)(ws + WX1_OFF))[u];
    const float  bout0 = bout[0];

    float c1 = 0.0f, c2 = 0.0f, xv_fut = 0.0f;
    unsigned phase = 0;

    for (int t = 0; t < TT; ++t) {
        const int p = t & 1;
        const float* h1prev = ws + H1_OFF + p       * (Hdim * Bdim);
        float*       h1next = ws + H1_OFF + (p ^ 1) * (Hdim * Bdim);
        const float* h2prev = ws + H2_OFF + p       * (Hdim * Bdim);
        float*       h2next = ws + H2_OFF + (p ^ 1) * (Hdim * Bdim);

        float xv = (t < Tdim) ? ws[XT_OFF + t * Bdim + bcol] : xv_fut;

        // ---- cell 1 ----
        float ai = fmaf(wx1.x, xv, bias1.x);
        float af = fmaf(wx1.y, xv, bias1.y);
        float ag = fmaf(wx1.z, xv, bias1.z);
        float ao = fmaf(wx1.w, xv, bias1.w);
        matvec4(h1prev, wl1, half, lane, tid, ai, af, ag, ao, hlds);

        float i1 = sigm(ai), f1 = sigm(af), g1 = tanh_fast(ag), o1 = sigm(ao);
        c1 = fmaf(f1, c1, i1 * g1);
        float h1v = o1 * tanh_fast(c1);
        h1next[(size_t)u * Bdim + bcol] = h1v;

        grid_barrier(arr, rel, ++phase);        // h1(t) visible

        // ---- cell 2 ----
        ai = bias2.x; af = bias2.y; ag = bias2.z; ao = bias2.w;
        matvec4(h1next, wl2i, half, lane, tid, ai, af, ag, ao, hlds);
        matvec4(h2prev, wl2h, half, lane, tid, ai, af, ag, ao, hlds);

        float i2 = sigm(ai), f2 = sigm(af), g2 = tanh_fast(ag), o2 = sigm(ao);
        c2 = fmaf(f2, c2, i2 * g2);
        float h2v = o2 * tanh_fast(c2);
        h2next[(size_t)u * Bdim + bcol] = h2v;

        grid_barrier(arr, rel, ++phase);        // h2(t) visible

        // ---- output ----
        if (t < Tdim - 1) {
            if (bid < 2) {                       // cheap k-split dot, off the hot path
                float acc = 0.0f;
                const float* hb = h2next + bcol;
                const int k0 = w * 128;
                #pragma unroll 8
                for (int kk = 0; kk < 128; ++kk)
                    acc = fmaf(hb[(size_t)(k0 + kk) * Bdim], wout_lds[k0 + kk], acc);
                partial[w][lane] = acc;
                __syncthreads();
                if (w == 0) {
                    out[(size_t)bcol * TT + t] = partial[0][lane] + partial[1][lane]
                                               + partial[2][lane] + partial[3][lane] + bout0;
                }
                __syncthreads();
            }
        } else {
            // future phase: every block computes its own feedback -> no extra barrier
            float o = outdot(h2next, half, lane, tid, hlds, wout_lds) + bout0;
            if (bid < 2 && w == 0)
                out[(size_t)bcol * TT + t] = o;
            xv_fut = o;
        }
    }
}

extern "C" void kernel_launch(void* const* d_in, const int* in_sizes, int n_in,
                              void* d_out, int out_size, void* d_ws, size_t ws_size,
                              hipStream_t stream) {
    const float* x     = (const float*)d_in[0];
    const float* W_ih1 = (const float*)d_in[1];
    const float* W_hh1 = (const float*)d_in[2];
    const float* b_ih1 = (const float*)d_in[3];
    const float* b_hh1 = (const float*)d_in[4];
    const float* W_ih2 = (const float*)d_in[5];
    const float* W_hh2 = (const float*)d_in[6];
    const float* b_ih2 = (const float*)d_in[7];
    const float* b_hh2 = (const float*)d_in[8];
    const float* W_out = (const float*)d_in[9];
    const float* b_out = (const float*)d_in[10];
    float* ws  = (float*)d_ws;
    float* out = (float*)d_out;

    hipLaunchKernelGGL(lstm_prep, dim3(1024), dim3(256), 0, stream,
                       x, W_ih1, W_hh1, b_ih1, b_hh1, W_ih2, W_hh2, b_ih2, b_hh2, ws);
    hipLaunchKernelGGL(lstm_main, dim3(NBLK), dim3(NTHR), 0, stream,
                       ws, W_out, b_out, out);
}

// Round 3
// 19417.583 us; speedup vs baseline: 2.3663x; 2.3215x over previous
//
#include <hip/hip_runtime.h>
#include <cstdint>

// ---- problem dims (fixed by reference) ----
#define Hdim 512
#define Bdim 128
#define Tdim 512
#define FUT  32
#define TT   (Tdim + FUT)   // 544
#define NBLK 256
#define NTHR 256
#define HB   (Hdim * Bdim)

// ---- ws layout (float offsets) ----
#define WP1_OFF   0                                  // [512][512] float4 (gate-packed W_hh1)
#define WP2I_OFF  (WP1_OFF  + Hdim*Hdim*4)           // W_ih2 packed
#define WP2H_OFF  (WP2I_OFF + Hdim*Hdim*4)           // W_hh2 packed
#define B1P_OFF   (WP2H_OFF + Hdim*Hdim*4)           // [512] float4 bias1 (b_ih1+b_hh1)
#define B2P_OFF   (B1P_OFF  + Hdim*4)
#define WX1_OFF   (B2P_OFF  + Hdim*4)                // [512] float4 W_ih1 per gate
#define XT_OFF    (WX1_OFF  + Hdim*4)                // xT[t][b]  (512*128)
#define H1_OFF    (XT_OFF   + Tdim*Bdim)             // 2 ping-pong [512][128]; h1(s) in buf[s&1]
#define H2_OFF    (H1_OFF   + 2*HB)                  // h2(s) in buf[(s+1)&1]
#define OUTB_OFF  (H2_OFF   + 2*HB)                  // unused this round
#define ARR_OFF   (OUTB_OFF + Bdim)                  // [256] arrive flags (uint)
#define REL_OFF   (ARR_OFF  + NBLK)                  // release word
#define WS_FLOATS (REL_OFF  + 16)

__device__ __forceinline__ float sigm(float v) { return 1.0f / (1.0f + __expf(-v)); }
__device__ __forceinline__ float tanh_fast(float v) {
    v = fminf(fmaxf(v, -20.0f), 20.0f);
    float e = __expf(2.0f * v);
    return (e - 1.0f) / (e + 1.0f);
}

// ---- device-coherent (agent-scope, relaxed) accessors: read/write through the
//      non-coherent per-XCD L2 straight at the LLC. NO cache-wide fences needed.
__device__ __forceinline__ unsigned long long cohload64(const unsigned long long* p) {
    return __hip_atomic_load(p, __ATOMIC_RELAXED, __HIP_MEMORY_SCOPE_AGENT);
}
__device__ __forceinline__ float cohloadf(const float* p) {
    return __hip_atomic_load(p, __ATOMIC_RELAXED, __HIP_MEMORY_SCOPE_AGENT);
}
__device__ __forceinline__ void cohstoref(float* p, float v) {
    __hip_atomic_store(p, v, __ATOMIC_RELAXED, __HIP_MEMORY_SCOPE_AGENT);
}

// ---------- fence-free grid barrier ----------
// Release: __syncthreads() drains every wave's vmcnt (per __syncthreads semantics),
// so all coherent h-stores are device-visible before the arrive-flag store.
// Acquire: subsequent h-reads are themselves agent-scope loads (read-through),
// issued in-order after the poll branch -> no buffer_inv needed.
__device__ __forceinline__ void grid_barrier(unsigned* arr, unsigned* rel, unsigned phase) {
    __syncthreads();
    if (threadIdx.x == 0)
        __hip_atomic_store(&arr[blockIdx.x], phase, __ATOMIC_RELAXED, __HIP_MEMORY_SCOPE_AGENT);
    if (blockIdx.x == 0) {
        while (__hip_atomic_load(&arr[threadIdx.x], __ATOMIC_RELAXED, __HIP_MEMORY_SCOPE_AGENT) < phase)
            __builtin_amdgcn_s_sleep(1);
        __syncthreads();
        if (threadIdx.x == 0)
            __hip_atomic_store(rel, phase, __ATOMIC_RELAXED, __HIP_MEMORY_SCOPE_AGENT);
    } else if (threadIdx.x == 0) {
        while (__hip_atomic_load(rel, __ATOMIC_RELAXED, __HIP_MEMORY_SCOPE_AGENT) < phase)
            __builtin_amdgcn_s_sleep(1);
    }
    __syncthreads();
}

// ---------- one staged pass over a 512-vector h: up to 2 gate-matrices + out-dot ----------
// hsrc: [512][128] transposed h (device-coherent). wlA/wlB: per-wave gate-packed LDS weights.
template<bool WA, bool WB, bool WO>
__device__ __forceinline__ void pass_fn(const float* hsrc,
                                        const float4* wlA, const float4* wlB,
                                        const float* wout_lds,
                                        int half, int lane, int tid,
                                        float4& accA, float4& accB, float& oacc,
                                        float* hlds) {
    const unsigned long long* src = (const unsigned long long*)hsrc + half * 32; // 64-float half
    unsigned long long pre[16];
    #pragma unroll
    for (int p = 0; p < 16; ++p) {
        int idx = p * 256 + tid, r = idx >> 5, c = idx & 31;
        pre[p] = cohload64(src + (size_t)r * 64 + c);
    }
    for (int kc = 0; kc < Hdim; kc += 128) {
        __syncthreads();                               // prev readers of hlds done
        #pragma unroll
        for (int p = 0; p < 16; ++p)
            ((unsigned long long*)hlds)[p * 256 + tid] = pre[p];
        __syncthreads();                               // staging visible
        if (kc + 128 < Hdim) {                         // prefetch next chunk during compute
            #pragma unroll
            for (int p = 0; p < 16; ++p) {
                int idx = p * 256 + tid, r = idx >> 5, c = idx & 31;
                pre[p] = cohload64(src + (size_t)(kc + 128 + r) * 64 + c);
            }
        }
        #pragma unroll 8
        for (int kk = 0; kk < 128; ++kk) {
            float hv = hlds[kk * 64 + lane];           // 2 lanes/bank: free
            if (WA) { float4 wa = wlA[kc + kk];
                accA.x = fmaf(wa.x, hv, accA.x); accA.y = fmaf(wa.y, hv, accA.y);
                accA.z = fmaf(wa.z, hv, accA.z); accA.w = fmaf(wa.w, hv, accA.w); }
            if (WB) { float4 wb = wlB[kc + kk];
                accB.x = fmaf(wb.x, hv, accB.x); accB.y = fmaf(wb.y, hv, accB.y);
                accB.z = fmaf(wb.z, hv, accB.z); accB.w = fmaf(wb.w, hv, accB.w); }
            if (WO) oacc = fmaf(wout_lds[kc + kk], hv, oacc);
        }
    }
}

__device__ __forceinline__ float cell_update(float4 a, float& c) {
    float i = sigm(a.x), f = sigm(a.y), g = tanh_fast(a.z), o = sigm(a.w);
    c = fmaf(f, c, i * g);
    return o * tanh_fast(c);
}

// ---------- prep: pack weights gate-major, transpose x, zero state/flags ----------
__global__ void lstm_prep(const float* __restrict__ x,
                          const float* __restrict__ W_ih1, const float* __restrict__ W_hh1,
                          const float* __restrict__ b_ih1, const float* __restrict__ b_hh1,
                          const float* __restrict__ W_ih2, const float* __restrict__ W_hh2,
                          const float* __restrict__ b_ih2, const float* __restrict__ b_hh2,
                          float* __restrict__ ws) {
    int i = blockIdx.x * blockDim.x + threadIdx.x;
    if (i < Hdim * Hdim) {
        int u = i >> 9, k = i & (Hdim - 1);
        float4 w1, w2i, w2h;
        w1.x  = W_hh1[(0 * Hdim + u) * Hdim + k];  w1.y  = W_hh1[(1 * Hdim + u) * Hdim + k];
        w1.z  = W_hh1[(2 * Hdim + u) * Hdim + k];  w1.w  = W_hh1[(3 * Hdim + u) * Hdim + k];
        w2i.x = W_ih2[(0 * Hdim + u) * Hdim + k];  w2i.y = W_ih2[(1 * Hdim + u) * Hdim + k];
        w2i.z = W_ih2[(2 * Hdim + u) * Hdim + k];  w2i.w = W_ih2[(3 * Hdim + u) * Hdim + k];
        w2h.x = W_hh2[(0 * Hdim + u) * Hdim + k];  w2h.y = W_hh2[(1 * Hdim + u) * Hdim + k];
        w2h.z = W_hh2[(2 * Hdim + u) * Hdim + k];  w2h.w = W_hh2[(3 * Hdim + u) * Hdim + k];
        ((float4*)(ws + WP1_OFF))[i]  = w1;
        ((float4*)(ws + WP2I_OFF))[i] = w2i;
        ((float4*)(ws + WP2H_OFF))[i] = w2h;
    }
    if (i < Hdim) {
        float4 bb1 = { b_ih1[i] + b_hh1[i],               b_ih1[Hdim+i] + b_hh1[Hdim+i],
                       b_ih1[2*Hdim+i] + b_hh1[2*Hdim+i], b_ih1[3*Hdim+i] + b_hh1[3*Hdim+i] };
        float4 bb2 = { b_ih2[i] + b_hh2[i],               b_ih2[Hdim+i] + b_hh2[Hdim+i],
                       b_ih2[2*Hdim+i] + b_hh2[2*Hdim+i], b_ih2[3*Hdim+i] + b_hh2[3*Hdim+i] };
        float4 wx  = { W_ih1[i], W_ih1[Hdim+i], W_ih1[2*Hdim+i], W_ih1[3*Hdim+i] };
        ((float4*)(ws + B1P_OFF))[i] = bb1;
        ((float4*)(ws + B2P_OFF))[i] = bb2;
        ((float4*)(ws + WX1_OFF))[i] = wx;
    }
    if (i < Tdim * Bdim) {          // xT + zero buf0 of h1,h2 (h1(0-pre) / h2(-1))
        int t = i >> 7, b = i & 127;
        ws[XT_OFF + i] = x[b * Tdim + t];
        ws[H1_OFF + i] = 0.0f;
        ws[H2_OFF + i] = 0.0f;
    }
    if (i < Bdim) ws[OUTB_OFF + i] = 0.0f;
    if (i < NBLK + 16)
        ((unsigned*)(ws + ARR_OFF))[i] = 0u;
}

// ---------- persistent main kernel ----------
__global__ __launch_bounds__(NTHR) void lstm_main(float* ws,
                                                  const float* __restrict__ Wout,
                                                  const float* __restrict__ bout,
                                                  float* __restrict__ out) {
    const int tid  = threadIdx.x;
    const int bid  = blockIdx.x;
    const int w    = tid >> 6;                  // wave 0..3 = local unit
    const int lane = tid & 63;
    const int ug   = bid >> 1;                  // unit group 0..127
    const int half = bid & 1;                   // batch half
    const int u    = __builtin_amdgcn_readfirstlane(ug * 4 + w);
    const int bcol = half * 64 + lane;
    const bool douter = (bid < 2);              // blocks that own the out-projection

    __shared__ float4 wlds4[4 * 3 * Hdim];      // 96 KB weights (L2-inv-immune by nature)
    __shared__ float  hlds[128 * 64];           // 32 KB h staging
    __shared__ float  wout_lds[Hdim];           // 2 KB

    unsigned* arr = (unsigned*)(ws + ARR_OFF);
    unsigned* rel = (unsigned*)(ws + REL_OFF);
    float* h1b0 = ws + H1_OFF;                  // h1(s) -> h1b[s&1]
    float* h1b1 = ws + H1_OFF + HB;
    float* h2b0 = ws + H2_OFF;                  // h2(s) -> h2b[(s+1)&1]
    float* h2b1 = ws + H2_OFF + HB;

    // ---- one-time: weights -> LDS (plain loads; prep-written, safe at dispatch boundary)
    {
        const float4* wsrc0 = (const float4*)(ws + WP1_OFF);
        const float4* wsrc1 = (const float4*)(ws + WP2I_OFF);
        const float4* wsrc2 = (const float4*)(ws + WP2H_OFF);
        for (int w2 = 0; w2 < 4; ++w2) {
            const size_t ubase = (size_t)(ug * 4 + w2) * Hdim;
            #pragma unroll
            for (int p = 0; p < 2; ++p) {
                int k = p * 256 + tid;
                wlds4[(w2 * 3 + 0) * Hdim + k] = wsrc0[ubase + k];
                wlds4[(w2 * 3 + 1) * Hdim + k] = wsrc1[ubase + k];
                wlds4[(w2 * 3 + 2) * Hdim + k] = wsrc2[ubase + k];
            }
        }
        wout_lds[tid]       = Wout[tid];
        wout_lds[256 + tid] = Wout[256 + tid];
    }

    const float4* wl1  = wlds4 + (w * 3 + 0) * Hdim;
    const float4* wl2i = wlds4 + (w * 3 + 1) * Hdim;
    const float4* wl2h = wlds4 + (w * 3 + 2) * Hdim;
    const float4 bias1 = ((const float4*)(ws + B1P_OFF))[u];
    const float4 bias2 = ((const float4*)(ws + B2P_OFF))[u];
    const float4 wx1   = ((const float4*)(ws + WX1_OFF))[u];
    const float  bout0 = bout[0];

    float c1 = 0.0f, c2 = 0.0f;
    float4 dummy;
    unsigned phase = 0;

    // ---- pre-phase: C1(0) (h1(-1)=0 -> no matvec), publish h1(0) into buf0
    {
        float xv = ws[XT_OFF + bcol];
        float4 a1 = { fmaf(wx1.x, xv, bias1.x), fmaf(wx1.y, xv, bias1.y),
                      fmaf(wx1.z, xv, bias1.z), fmaf(wx1.w, xv, bias1.w) };
        float h1v = cell_update(a1, c1);
        cohstoref(&h1b0[(size_t)u * Bdim + bcol], h1v);
    }
    grid_barrier(arr, rel, ++phase);

    // ---- main pipelined phases t=0..510: C1(t+1) + C2(t) (+ O(t-1) on blocks 0/1)
    for (int t = 0; t < 511; ++t) {
        const float* h1cur = (t & 1) ? h1b1 : h1b0;            // h1(t)
        float*       h1nxt = (t & 1) ? h1b0 : h1b1;            // h1(t+1)
        const float* h2prv = (t & 1) ? h2b1 : h2b0;            // h2(t-1)
        float*       h2nxt = (t & 1) ? h2b0 : h2b1;            // h2(t)

        float xv = ws[XT_OFF + (t + 1) * Bdim + bcol];         // plain (read-only, L2-warm)
        float4 a1 = { fmaf(wx1.x, xv, bias1.x), fmaf(wx1.y, xv, bias1.y),
                      fmaf(wx1.z, xv, bias1.z), fmaf(wx1.w, xv, bias1.w) };
        float4 a2 = bias2;
        float oacc = 0.0f;

        // h1(t) staged once: feeds C1(t+1) (wl1) and C2(t)-ih (wl2i)
        pass_fn<true, true, false>(h1cur, wl1, wl2i, wout_lds, half, lane, tid,
                                   a1, a2, oacc, hlds);
        // h2(t-1) staged once: feeds C2(t)-hh (+ out-dot on blocks 0/1)
        if (douter && t >= 1) {
            pass_fn<true, false, true>(h2prv, wl2h, wl2h, wout_lds, half, lane, tid,
                                       a2, dummy, oacc, hlds);
            if (w == 0) out[(size_t)bcol * TT + (t - 1)] = oacc + bout0;
        } else {
            pass_fn<true, false, false>(h2prv, wl2h, wl2h, wout_lds, half, lane, tid,
                                        a2, dummy, oacc, hlds);
        }

        float h1v = cell_update(a1, c1);
        cohstoref(&h1nxt[(size_t)u * Bdim + bcol], h1v);
        float h2v = cell_update(a2, c2);
        cohstoref(&h2nxt[(size_t)u * Bdim + bcol], h2v);

        grid_barrier(arr, rel, ++phase);
    }

    // ---- phase 511: C2(511) (+ O(510) on blocks 0/1)
    {
        const int t = 511;
        const float* h1cur = h1b1;                             // h1(511)
        const float* h2prv = h2b1;                             // h2(510)
        float*       h2nxt = h2b0;                             // h2(511)
        float4 a2 = bias2;
        float oacc = 0.0f;
        pass_fn<true, false, false>(h1cur, wl2i, wl2i, wout_lds, half, lane, tid,
                                    a2, dummy, oacc, hlds);
        if (douter) {
            pass_fn<true, false, true>(h2prv, wl2h, wl2h, wout_lds, half, lane, tid,
                                       a2, dummy, oacc, hlds);
            if (w == 0) out[(size_t)bcol * TT + (t - 1)] = oacc + bout0;
        } else {
            pass_fn<true, false, false>(h2prv, wl2h, wl2h, wout_lds, half, lane, tid,
                                        a2, dummy, oacc, hlds);
        }
        float h2v = cell_update(a2, c2);
        cohstoref(&h2nxt[(size_t)u * Bdim + bcol], h2v);
        grid_barrier(arr, rel, ++phase);
    }

    // ---- future phase t=512..543: 2 barriers/step, every block computes its own feedback
    for (int t = 512; t < TT; ++t) {
        const float* h1prv = ((t - 1) & 1) ? h1b1 : h1b0;      // h1(t-1)
        float*       h1nxt = (t & 1) ? h1b1 : h1b0;            // h1(t)
        const float* h2prv = (t & 1) ? h2b1 : h2b0;            // h2(t-1)
        float*       h2nxt = (t & 1) ? h2b0 : h2b1;            // h2(t)

        // F-a: O(t-1) locally (all blocks, all waves -> identical per bcol), then C1(t)
        float oacc = 0.0f;
        pass_fn<false, false, true>(h2prv, wl1, wl1, wout_lds, half, lane, tid,
                                    dummy, dummy, oacc, hlds);
        float xv = oacc + bout0;
        if (douter && w == 0) out[(size_t)bcol * TT + (t - 1)] = xv;

        float4 a1 = { fmaf(wx1.x, xv, bias1.x), fmaf(wx1.y, xv, bias1.y),
                      fmaf(wx1.z, xv, bias1.z), fmaf(wx1.w, xv, bias1.w) };
        pass_fn<true, false, false>(h1prv, wl1, wl1, wout_lds, half, lane, tid,
                                    a1, dummy, oacc, hlds);
        float h1v = cell_update(a1, c1);
        cohstoref(&h1nxt[(size_t)u * Bdim + bcol], h1v);
        grid_barrier(arr, rel, ++phase);

        // F-b: C2(t)
        const float* h1cur = h1nxt;
        float4 a2 = bias2;
        pass_fn<true, false, false>(h1cur, wl2i, wl2i, wout_lds, half, lane, tid,
                                    a2, dummy, oacc, hlds);
        pass_fn<true, false, false>(h2prv, wl2h, wl2h, wout_lds, half, lane, tid,
                                    a2, dummy, oacc, hlds);
        float h2v = cell_update(a2, c2);
        cohstoref(&h2nxt[(size_t)u * Bdim + bcol], h2v);
        grid_barrier(arr, rel, ++phase);
    }

    // ---- final O(543) (h2(543) in buf0, published at last barrier)
    if (douter) {
        float oacc = 0.0f;
        pass_fn<false, false, true>(h2b0, wl1, wl1, wout_lds, half, lane, tid,
                                    dummy, dummy, oacc, hlds);
        if (w == 0) out[(size_t)bcol * TT + (TT - 1)] = oacc + bout0;
    }
}

extern "C" void kernel_launch(void* const* d_in, const int* in_sizes, int n_in,
                              void* d_out, int out_size, void* d_ws, size_t ws_size,
                              hipStream_t stream) {
    const float* x     = (const float*)d_in[0];
    const float* W_ih1 = (const float*)d_in[1];
    const float* W_hh1 = (const float*)d_in[2];
    const float* b_ih1 = (const float*)d_in[3];
    const float* b_hh1 = (const float*)d_in[4];
    const float* W_ih2 = (const float*)d_in[5];
    const float* W_hh2 = (const float*)d_in[6];
    const float* b_ih2 = (const float*)d_in[7];
    const float* b_hh2 = (const float*)d_in[8];
    const float* W_out = (const float*)d_in[9];
    const float* b_out = (const float*)d_in[10];
    float* ws  = (float*)d_ws;
    float* out = (float*)d_out;

    hipLaunchKernelGGL(lstm_prep, dim3(1024), dim3(256), 0, stream,
                       x, W_ih1, W_hh1, b_ih1, b_hh1, W_ih2, W_hh2, b_ih2, b_hh2, ws);
    hipLaunchKernelGGL(lstm_main, dim3(NBLK), dim3(NTHR), 0, stream,
                       ws, W_out, b_out, out);
}